// Round 1
// baseline (46798.938 us; speedup 1.0000x reference)
//
#include <hip/hip_runtime.h>
#include <math.h>

#define TMAX 16384
#define MDIM 16
#define SDIM 2048
#define NTHR 1024

// ---- wave (64-lane) reductions via shfl ----
__device__ __forceinline__ float waveMax(float v) {
    #pragma unroll
    for (int o = 32; o > 0; o >>= 1) v = fmaxf(v, __shfl_xor(v, o, 64));
    return v;
}
__device__ __forceinline__ float waveSum(float v) {
    #pragma unroll
    for (int o = 32; o > 0; o >>= 1) v += __shfl_xor(v, o, 64);
    return v;
}
__device__ __forceinline__ double waveSumD(double v) {
    #pragma unroll
    for (int o = 32; o > 0; o >>= 1) v += __shfl_xor(v, o, 64);
    return v;
}

// Factorial-HMM forward pass, scaled linear domain, single workgroup.
// State s = d1*128 + d2*8 + d3  (d1<16, d2<16, d3<8). Thread owns states 2*tid, 2*tid+1.
__global__ __launch_bounds__(NTHR)
void fhmm_forward_kernel(const int* __restrict__ x,
                         const float* __restrict__ lam1,
                         const float* __restrict__ lam2,
                         const float* __restrict__ lam3,
                         const float* __restrict__ logA1,
                         const float* __restrict__ logA2,
                         const float* __restrict__ logA3,
                         const float* __restrict__ logpi1,
                         const float* __restrict__ logpi2,
                         const float* __restrict__ logpi3,
                         float* __restrict__ out)
{
    __shared__ float sA1[256];     // A1[d1][p1] row-major (read broadcast, wave-uniform d1)
    __shared__ float sA2T[256];    // A2 transposed: sA2T[p2*16 + d2] (conflict-free lane reads)
    __shared__ float sA3[64];      // A3[d3][p3] row-major (<=2-way conflict: free)
    __shared__ float alpha[SDIM];
    __shared__ float c1buf[SDIM];  // [d1*128 + p2*8 + p3]
    __shared__ float c2buf[SDIM];  // [d1*128 + d2*8 + p3]
    __shared__ float wmaxEm[16];
    __shared__ float wmaxA[16];
    __shared__ float lgtbl[32];
    __shared__ double lgpart[16];
    __shared__ float sredf[16];

    const int tid  = threadIdx.x;
    const int lane = tid & 63;
    const int wv   = tid >> 6;
    const int s0   = tid * 2;            // first owned state (even)
    const int d1   = s0 >> 7;
    const int d2   = (s0 >> 3) & 15;
    const int d3   = s0 & 7;             // even; pair = d3, d3+1

    // Stage-1 ownership: output rows {r1a, r1a+1} x column c1col (p2p3)
    const int r1a   = (tid >> 7) * 2;
    const int c1col = tid & 127;
    // Stage-2 ownership: d1 = d1s2, output d2 rows {r2a, r2a+1}, column p3s2
    const int d1s2 = tid >> 6;
    const int r2a  = ((tid >> 3) & 7) * 2;
    const int p3s2 = tid & 7;

    // ---- init: transition matrices (exp), lgamma table ----
    if (tid < 256) {
        sA1[tid] = __expf(logA1[tid]);
        // sA2T[p*16+d] = exp(logA2[d*16+p])
        sA2T[tid] = __expf(logA2[(tid & 15) * 16 + (tid >> 4)]);
    } else if (tid < 320) {
        sA3[tid - 256] = __expf(logA3[tid - 256]);
    } else if (tid < 352) {
        lgtbl[tid - 320] = lgammaf((float)(tid - 320) + 1.0f);
    }

    // ---- per-thread emission params in registers ----
    float rl0[16], rl1[16];
    float lamsum0 = 0.f, lamsum1 = 0.f;
    #pragma unroll
    for (int m = 0; m < MDIM; ++m) {
        float l12 = lam1[d1 * MDIM + m] + lam2[d2 * MDIM + m];
        float la  = l12 + lam3[d3 * MDIM + m];
        float lb  = l12 + lam3[(d3 + 1) * MDIM + m];
        lamsum0 += la; lamsum1 += lb;
        rl0[m] = __logf(la);
        rl1[m] = __logf(lb);
    }
    __syncthreads();

    // ---- sum_t sum_m lgamma(x+1): uniform over states, subtract at end ----
    {
        double lg = 0.0;
        const int4* x4 = (const int4*)x;
        for (int i = tid; i < TMAX * MDIM / 4; i += NTHR) {
            int4 v = x4[i];
            lg += (double)(lgtbl[v.x & 31] + lgtbl[v.y & 31] +
                           lgtbl[v.z & 31] + lgtbl[v.w & 31]);
        }
        lg = waveSumD(lg);
        if (lane == 0) lgpart[wv] = lg;
    }

    // ---- t = 0: alpha_0 = exp(em0 + logpi - M0) ----
    double OFF;
    {
        float dot0 = 0.f, dot1 = 0.f;
        #pragma unroll
        for (int m = 0; m < MDIM; ++m) {
            float xf = (float)x[m];
            dot0 += xf * rl0[m]; dot1 += xf * rl1[m];
        }
        float e0 = dot0 - lamsum0, e1 = dot1 - lamsum1;
        float lp12 = logpi1[d1] + logpi2[d2];
        float va = e0 + lp12 + logpi3[d3];
        float vb = e1 + lp12 + logpi3[d3 + 1];
        float wm = waveMax(fmaxf(va, vb));
        if (lane == 0) wmaxEm[wv] = wm;
        __syncthreads();
        float M0 = wmaxEm[0];
        #pragma unroll
        for (int i = 1; i < 16; ++i) M0 = fmaxf(M0, wmaxEm[i]);
        float u0 = __expf(va - M0), u1 = __expf(vb - M0);
        alpha[s0] = u0; alpha[s0 + 1] = u1;
        float am = waveMax(fmaxf(u0, u1));
        if (lane == 0) wmaxA[wv] = am;
        OFF = (double)M0;
        __syncthreads();
    }

    // ---- x prefetch (wave-uniform -> scalar loads), one step ahead ----
    const int4* xv = (const int4*)x;
    int4 xc[4];
    #pragma unroll
    for (int q = 0; q < 4; ++q) xc[q] = xv[4 + q];   // t = 1

    // ---- main sequential recurrence ----
    for (int t = 1; t < TMAX; ++t) {
        // prefetch x[t+1]
        int tn = (t + 1 < TMAX) ? (t + 1) : t;
        int4 xn[4];
        #pragma unroll
        for (int q = 0; q < 4; ++q) xn[q] = xv[tn * 4 + q];

        // scale factor from previous step's alpha max
        float mp = wmaxA[0];
        #pragma unroll
        for (int i = 1; i < 16; ++i) mp = fmaxf(mp, wmaxA[i]);
        float invm = __builtin_amdgcn_rcpf(mp);
        OFF += (double)__logf(mp);

        // Stage 1: c1[d1, p2p3] = invm * sum_p1 A1[d1,p1] * alpha[p1, p2p3]
        {
            float a0 = 0.f, a1 = 0.f;
            #pragma unroll
            for (int p1 = 0; p1 < 16; ++p1) {
                float av = alpha[p1 * 128 + c1col];
                a0 += sA1[r1a * 16 + p1] * av;        // wave-uniform broadcast
                a1 += sA1[(r1a + 1) * 16 + p1] * av;
            }
            c1buf[r1a * 128 + c1col]       = a0 * invm;
            c1buf[(r1a + 1) * 128 + c1col] = a1 * invm;
        }

        // emission dot for step t (pure VALU, overlaps stage 1 LDS)
        int xi[16];
        xi[0]=xc[0].x; xi[1]=xc[0].y; xi[2]=xc[0].z; xi[3]=xc[0].w;
        xi[4]=xc[1].x; xi[5]=xc[1].y; xi[6]=xc[1].z; xi[7]=xc[1].w;
        xi[8]=xc[2].x; xi[9]=xc[2].y; xi[10]=xc[2].z; xi[11]=xc[2].w;
        xi[12]=xc[3].x; xi[13]=xc[3].y; xi[14]=xc[3].z; xi[15]=xc[3].w;
        float dd0 = 0.f, dd1 = 0.f;
        #pragma unroll
        for (int m = 0; m < MDIM; ++m) {
            float xf = (float)xi[m];
            dd0 += xf * rl0[m]; dd1 += xf * rl1[m];
        }
        float em0 = dd0 - lamsum0, em1 = dd1 - lamsum1;
        float wmE = waveMax(fmaxf(em0, em1));
        if (lane == 0) wmaxEm[wv] = wmE;
        __syncthreads();   // c1 complete, wmaxEm complete

        // Stage 2: c2[d1, d2, p3] = sum_p2 A2[d2,p2] * c1[d1, p2, p3]
        {
            float b0 = 0.f, b1 = 0.f;
            #pragma unroll
            for (int p2 = 0; p2 < 16; ++p2) {
                float cv = c1buf[d1s2 * 128 + p2 * 8 + p3s2];  // 8-lane broadcast
                b0 += sA2T[p2 * 16 + r2a] * cv;
                b1 += sA2T[p2 * 16 + r2a + 1] * cv;
            }
            c2buf[d1s2 * 128 + r2a * 8 + p3s2]       = b0;
            c2buf[d1s2 * 128 + (r2a + 1) * 8 + p3s2] = b1;
        }
        __syncthreads();   // c2 complete

        // Stage 3 + pointwise: alpha_new[s] = exp(em - Mt) * sum_p3 A3[d3,p3]*c2[d1,d2,p3]
        float Mt = wmaxEm[0];
        #pragma unroll
        for (int i = 1; i < 16; ++i) Mt = fmaxf(Mt, wmaxEm[i]);
        float g0 = 0.f, g1 = 0.f;
        const int cbase = s0 & ~7;
        #pragma unroll
        for (int p3 = 0; p3 < 8; ++p3) {
            float cv = c2buf[cbase + p3];
            g0 += sA3[d3 * 8 + p3] * cv;
            g1 += sA3[(d3 + 1) * 8 + p3] * cv;
        }
        float nu0 = __expf(em0 - Mt) * g0;
        float nu1 = __expf(em1 - Mt) * g1;
        alpha[s0] = nu0; alpha[s0 + 1] = nu1;
        OFF += (double)Mt;
        float wmA = waveMax(fmaxf(nu0, nu1));
        if (lane == 0) wmaxA[wv] = wmA;

        // rotate x prefetch
        #pragma unroll
        for (int q = 0; q < 4; ++q) xc[q] = xn[q];
        __syncthreads();   // alpha, wmaxA complete
    }

    // ---- final: logp = OFF + log(sum_s alpha) - lgam_total ----
    {
        float su = alpha[s0] + alpha[s0 + 1];
        su = waveSum(su);
        if (lane == 0) sredf[wv] = su;
        __syncthreads();
        if (tid == 0) {
            float tot = 0.f;
            #pragma unroll
            for (int i = 0; i < 16; ++i) tot += sredf[i];
            double lgt = 0.0;
            #pragma unroll
            for (int i = 0; i < 16; ++i) lgt += lgpart[i];
            double res = OFF + (double)__logf(tot) - lgt;
            out[0] = (float)res;
        }
    }
}

extern "C" void kernel_launch(void* const* d_in, const int* in_sizes, int n_in,
                              void* d_out, int out_size, void* d_ws, size_t ws_size,
                              hipStream_t stream) {
    const int*   x      = (const int*)  d_in[0];
    const float* lam1   = (const float*)d_in[1];
    const float* lam2   = (const float*)d_in[2];
    const float* lam3   = (const float*)d_in[3];
    const float* logA1  = (const float*)d_in[4];
    const float* logA2  = (const float*)d_in[5];
    const float* logA3  = (const float*)d_in[6];
    const float* logpi1 = (const float*)d_in[7];
    const float* logpi2 = (const float*)d_in[8];
    const float* logpi3 = (const float*)d_in[9];
    float* out = (float*)d_out;

    fhmm_forward_kernel<<<dim3(1), dim3(NTHR), 0, stream>>>(
        x, lam1, lam2, lam3, logA1, logA2, logA3, logpi1, logpi2, logpi3, out);
}

// Round 2
// 28248.853 us; speedup vs baseline: 1.6567x; 1.6567x over previous
//
#include <hip/hip_runtime.h>
#include <math.h>

#define TMAX 16384
#define MDIM 16
#define NTHR 1024

// ---- DPP-based full-wave (64-lane) max: VALU pipe only, no LDS traffic ----
template<int CTRL>
__device__ __forceinline__ float fmax_dpp(float v) {
    int o = __builtin_amdgcn_update_dpp(__float_as_int(v), __float_as_int(v),
                                        CTRL, 0xf, 0xf, false);
    return fmaxf(v, __int_as_float(o));
}
__device__ __forceinline__ float waveMax64(float v) {
    v = fmax_dpp<0x111>(v);   // row_shr:1
    v = fmax_dpp<0x112>(v);   // row_shr:2
    v = fmax_dpp<0x114>(v);   // row_shr:4
    v = fmax_dpp<0x118>(v);   // row_shr:8
    v = fmax_dpp<0x142>(v);   // row_bcast:15
    v = fmax_dpp<0x143>(v);   // row_bcast:31
    return __int_as_float(__builtin_amdgcn_readlane(__float_as_int(v), 63));
}
__device__ __forceinline__ float rfl(float v) {   // force wave-uniform -> SGPR
    return __int_as_float(__builtin_amdgcn_readfirstlane(__float_as_int(v)));
}
__device__ __forceinline__ float waveSumF(float v) {
    #pragma unroll
    for (int o = 32; o > 0; o >>= 1) v += __shfl_xor(v, o, 64);
    return v;
}
__device__ __forceinline__ double waveSumD(double v) {
    #pragma unroll
    for (int o = 32; o > 0; o >>= 1) v += __shfl_xor(v, o, 64);
    return v;
}

// Factorial-HMM forward pass, scaled linear domain, single workgroup of 16 waves.
// State s = d1*128 + d2*8 + d3 (d1<16, d2<16, d3<8). Thread owns states 2*tid, 2*tid+1.
__global__ __launch_bounds__(NTHR)
void fhmm_forward_kernel(const int* __restrict__ x,
                         const float* __restrict__ lam1,
                         const float* __restrict__ lam2,
                         const float* __restrict__ lam3,
                         const float* __restrict__ logA1,
                         const float* __restrict__ logA2,
                         const float* __restrict__ logA3,
                         const float* __restrict__ logpi1,
                         const float* __restrict__ logpi2,
                         const float* __restrict__ logpi3,
                         float* __restrict__ out)
{
    __shared__ __align__(16) float alpha[2048];     // natural layout [p1*128 + (d2*8+d3)]
    __shared__ __align__(16) float c1buf[16 * 136]; // transposed [d1][p3*16 + p2], stride 136
    __shared__ float c2buf[256 * 9];                // [(d1*16+d2)*9 + p3]
    __shared__ float wmEm[16];
    __shared__ float wmA[16];
    __shared__ float sD[1];
    __shared__ float lgtbl[32];
    __shared__ double lgpart[16];
    __shared__ float sredf[16];

    const int tid  = threadIdx.x;
    const int lane = tid & 63;
    const int wv   = tid >> 6;
    const int s0   = tid * 2;
    const int d1   = s0 >> 7;
    const int d2e  = (s0 >> 3) & 15;
    const int d3   = s0 & 7;              // even; pair = d3, d3+1

    // Stage-1 ownership: d1-rows {r1, r1+1} (wave-uniform), column c1col = p2*8+p3
    const int r1    = (wv >> 1) * 2;
    const int c1col = (wv & 1) * 64 + lane;
    const int c1wr  = r1 * 136 + (c1col & 7) * 16 + (c1col >> 3); // transposed write
    // Stage-2 ownership: d2-rows {d2s, d2s+1} (wave-uniform), column (d1s, p3s)
    const int d2s  = (wv & 7) * 2;
    const int scol = (wv >> 3) * 64 + lane;
    const int d1s  = scol >> 3;
    const int p3s  = scol & 7;
    const int c1rd = d1s * 136 + p3s * 16;           // + p2 (contiguous -> b128)
    const int c2wr = (d1s * 16 + d2s) * 9 + p3s;
    // Stage-3 ownership: same states as emission; c2 column = tid>>2 (4-lane broadcast)
    const int c2rd = (tid >> 2) * 9;

    // ---- init: lgamma table ----
    if (tid < 32) lgtbl[tid] = lgammaf((float)tid + 1.0f);

    // ---- A rows hoisted to registers (A1/A2 wave-uniform -> SGPR, A3 per-lane VGPR) ----
    float sa1a[16], sa1b[16], sa2a[16], sa2b[16];
    #pragma unroll
    for (int p = 0; p < 16; ++p) {
        sa1a[p] = rfl(__expf(logA1[r1 * 16 + p]));
        sa1b[p] = rfl(__expf(logA1[(r1 + 1) * 16 + p]));
        sa2a[p] = rfl(__expf(logA2[d2s * 16 + p]));
        sa2b[p] = rfl(__expf(logA2[(d2s + 1) * 16 + p]));
    }
    float a3a[8], a3b[8];
    #pragma unroll
    for (int p = 0; p < 8; ++p) {
        a3a[p] = __expf(logA3[d3 * 8 + p]);
        a3b[p] = __expf(logA3[(d3 + 1) * 8 + p]);
    }

    // ---- per-thread emission params in registers ----
    float rl0[16], rl1[16];
    float lamsum0 = 0.f, lamsum1 = 0.f;
    #pragma unroll
    for (int m = 0; m < MDIM; ++m) {
        float l12 = lam1[d1 * MDIM + m] + lam2[d2e * MDIM + m];
        float la  = l12 + lam3[d3 * MDIM + m];
        float lb  = l12 + lam3[(d3 + 1) * MDIM + m];
        lamsum0 += la; lamsum1 += lb;
        rl0[m] = __logf(la);
        rl1[m] = __logf(lb);
    }
    __syncthreads();

    // ---- sum_t sum_m lgamma(x+1): state-uniform, subtract at end ----
    {
        double lg = 0.0;
        const int4* x4 = (const int4*)x;
        for (int i = tid; i < TMAX * MDIM / 4; i += NTHR) {
            int4 v = x4[i];
            lg += (double)(lgtbl[v.x & 31] + lgtbl[v.y & 31] +
                           lgtbl[v.z & 31] + lgtbl[v.w & 31]);
        }
        lg = waveSumD(lg);
        if (lane == 0) lgpart[wv] = lg;
    }

    // ---- t = 0 ----
    double OFF = 0.0;
    {
        float dot0 = 0.f, dot1 = 0.f;
        #pragma unroll
        for (int m = 0; m < MDIM; ++m) {
            float xf = (float)x[m];
            dot0 += xf * rl0[m]; dot1 += xf * rl1[m];
        }
        float e0 = dot0 - lamsum0, e1 = dot1 - lamsum1;
        float lp12 = logpi1[d1] + logpi2[d2e];
        float va = e0 + lp12 + logpi3[d3];
        float vb = e1 + lp12 + logpi3[d3 + 1];
        float wm = waveMax64(fmaxf(va, vb));
        if (lane == 0) wmEm[wv] = wm;
        __syncthreads();
        float M0 = waveMax64(wmEm[lane & 15]);
        float u0 = __expf(va - M0), u1 = __expf(vb - M0);
        alpha[s0] = u0; alpha[s0 + 1] = u1;
        float wA = waveMax64(fmaxf(u0, u1));
        if (lane == 0) wmA[wv] = wA;
        if (tid == 0) OFF = (double)M0;
        __syncthreads();
    }

    // ---- x prefetch (wave-uniform), one step ahead ----
    const int4* xv = (const int4*)x;
    int4 xc[4];
    #pragma unroll
    for (int q = 0; q < 4; ++q) xc[q] = xv[4 + q];   // t = 1

    float mpLog = 0.f, Dv = 0.f;

    // ---- main sequential recurrence ----
    for (int t = 1; t < TMAX; ++t) {
        int tn = (t + 1 < TMAX) ? (t + 1) : t;
        int4 xn[4];
        #pragma unroll
        for (int q = 0; q < 4; ++q) xn[q] = xv[tn * 4 + q];

        // wave 0: combine previous-step alpha maxes (overlaps S1 window)
        if (wv == 0) {
            float mp = waveMax64(wmA[lane & 15]);
            mpLog = __logf(fmaxf(mp, 1e-30f));
        }

        // Stage 1: c1[d1][p3*16+p2] = sum_p1 A1[d1,p1] * alpha[p1*128 + p2*8+p3]
        {
            float acc0 = 0.f, acc1 = 0.f;
            #pragma unroll
            for (int p1 = 0; p1 < 16; ++p1) {
                float av = alpha[p1 * 128 + c1col];
                acc0 = fmaf(sa1a[p1], av, acc0);
                acc1 = fmaf(sa1b[p1], av, acc1);
            }
            c1buf[c1wr]       = acc0;
            c1buf[c1wr + 136] = acc1;
        }

        // emission dot for step t (pure VALU)
        int xi[16];
        xi[0]=xc[0].x; xi[1]=xc[0].y; xi[2]=xc[0].z; xi[3]=xc[0].w;
        xi[4]=xc[1].x; xi[5]=xc[1].y; xi[6]=xc[1].z; xi[7]=xc[1].w;
        xi[8]=xc[2].x; xi[9]=xc[2].y; xi[10]=xc[2].z; xi[11]=xc[2].w;
        xi[12]=xc[3].x; xi[13]=xc[3].y; xi[14]=xc[3].z; xi[15]=xc[3].w;
        float dd0 = 0.f, dd1 = 0.f;
        #pragma unroll
        for (int m = 0; m < MDIM; ++m) {
            float xf = (float)xi[m];
            dd0 += xf * rl0[m]; dd1 += xf * rl1[m];
        }
        float em0 = dd0 - lamsum0, em1 = dd1 - lamsum1;
        float wmE = waveMax64(fmaxf(em0, em1));
        if (lane == 0) wmEm[wv] = wmE;
        __syncthreads();   // B1: c1, wmEm ready

        // wave 0: combine em maxes, publish D = Mt + log(mp) (overlaps S2 window)
        if (wv == 0) {
            float Mt = waveMax64(wmEm[lane & 15]);
            Dv = Mt + mpLog;
            if (lane == 0) sD[0] = Dv;
        }

        // Stage 2: c2[(d1*16+d2)*9+p3] = sum_p2 A2[d2,p2] * c1[d1][p3*16+p2]
        {
            float b0 = 0.f, b1 = 0.f;
            const float4* c1v = (const float4*)(c1buf + c1rd);
            #pragma unroll
            for (int p = 0; p < 4; ++p) {
                float4 q = c1v[p];
                b0 = fmaf(sa2a[4*p+0], q.x, b0); b1 = fmaf(sa2b[4*p+0], q.x, b1);
                b0 = fmaf(sa2a[4*p+1], q.y, b0); b1 = fmaf(sa2b[4*p+1], q.y, b1);
                b0 = fmaf(sa2a[4*p+2], q.z, b0); b1 = fmaf(sa2b[4*p+2], q.z, b1);
                b0 = fmaf(sa2a[4*p+3], q.w, b0); b1 = fmaf(sa2b[4*p+3], q.w, b1);
            }
            c2buf[c2wr]     = b0;
            c2buf[c2wr + 9] = b1;
        }
        __syncthreads();   // B2: c2, sD ready

        // Stage 3 + pointwise: alpha_new = exp(em - D) * sum_p3 A3[d3,p3]*c2[col,p3]
        {
            float D = (wv == 0) ? Dv : sD[0];
            float g0 = 0.f, g1 = 0.f;
            #pragma unroll
            for (int p = 0; p < 8; ++p) {
                float cv = c2buf[c2rd + p];
                g0 = fmaf(a3a[p], cv, g0);
                g1 = fmaf(a3b[p], cv, g1);
            }
            float nu0 = __expf(em0 - D) * g0;
            float nu1 = __expf(em1 - D) * g1;
            alpha[s0] = nu0; alpha[s0 + 1] = nu1;
            float wA = waveMax64(fmaxf(nu0, nu1));
            if (lane == 0) wmA[wv] = wA;
            if (tid == 0) OFF += (double)D;
        }

        #pragma unroll
        for (int q = 0; q < 4; ++q) xc[q] = xn[q];
        __syncthreads();   // B3: alpha, wmA ready
    }

    // ---- final: logp = OFF + log(sum_s alpha) - lgam_total ----
    {
        float su = alpha[s0] + alpha[s0 + 1];
        su = waveSumF(su);
        if (lane == 0) sredf[wv] = su;
        __syncthreads();
        if (tid == 0) {
            float tot = 0.f;
            #pragma unroll
            for (int i = 0; i < 16; ++i) tot += sredf[i];
            double lgt = 0.0;
            #pragma unroll
            for (int i = 0; i < 16; ++i) lgt += lgpart[i];
            double res = OFF + (double)__logf(tot) - lgt;
            out[0] = (float)res;
        }
    }
}

extern "C" void kernel_launch(void* const* d_in, const int* in_sizes, int n_in,
                              void* d_out, int out_size, void* d_ws, size_t ws_size,
                              hipStream_t stream) {
    const int*   x      = (const int*)  d_in[0];
    const float* lam1   = (const float*)d_in[1];
    const float* lam2   = (const float*)d_in[2];
    const float* lam3   = (const float*)d_in[3];
    const float* logA1  = (const float*)d_in[4];
    const float* logA2  = (const float*)d_in[5];
    const float* logA3  = (const float*)d_in[6];
    const float* logpi1 = (const float*)d_in[7];
    const float* logpi2 = (const float*)d_in[8];
    const float* logpi3 = (const float*)d_in[9];
    float* out = (float*)d_out;

    fhmm_forward_kernel<<<dim3(1), dim3(NTHR), 0, stream>>>(
        x, lam1, lam2, lam3, logA1, logA2, logA3, logpi1, logpi2, logpi3, out);
}

// Round 3
// 22359.091 us; speedup vs baseline: 2.0931x; 1.2634x over previous
//
#include <hip/hip_runtime.h>
#include <math.h>

#define TMAX 16384
#define MDIM 16
#define NTHR 512

// ---- DPP-based full-wave (64-lane) max: VALU pipe only ----
template<int CTRL>
__device__ __forceinline__ float fmax_dpp(float v) {
    int o = __builtin_amdgcn_update_dpp(__float_as_int(v), __float_as_int(v),
                                        CTRL, 0xf, 0xf, false);
    return fmaxf(v, __int_as_float(o));
}
__device__ __forceinline__ float waveMax64(float v) {
    v = fmax_dpp<0x111>(v);   // row_shr:1
    v = fmax_dpp<0x112>(v);   // row_shr:2
    v = fmax_dpp<0x114>(v);   // row_shr:4
    v = fmax_dpp<0x118>(v);   // row_shr:8
    v = fmax_dpp<0x142>(v);   // row_bcast:15
    v = fmax_dpp<0x143>(v);   // row_bcast:31
    return __int_as_float(__builtin_amdgcn_readlane(__float_as_int(v), 63));
}
__device__ __forceinline__ float rfl(float v) {   // force wave-uniform -> SGPR
    return __int_as_float(__builtin_amdgcn_readfirstlane(__float_as_int(v)));
}
__device__ __forceinline__ float waveSumF(float v) {
    #pragma unroll
    for (int o = 32; o > 0; o >>= 1) v += __shfl_xor(v, o, 64);
    return v;
}
__device__ __forceinline__ double waveSumD(double v) {
    #pragma unroll
    for (int o = 32; o > 0; o >>= 1) v += __shfl_xor(v, o, 64);
    return v;
}

// Factorial-HMM forward, scaled linear domain. 512 threads / 8 waves, 4 states/thread.
// State s = d1*128 + d2*8 + d3. Thread owns s0=4*tid .. s0+3 (fixed d1,d2; d3 = 4*(tid&1)+k).
__global__ __launch_bounds__(NTHR, 2)
void fhmm_forward_kernel(const int* __restrict__ x,
                         const float* __restrict__ lam1,
                         const float* __restrict__ lam2,
                         const float* __restrict__ lam3,
                         const float* __restrict__ logA1,
                         const float* __restrict__ logA2,
                         const float* __restrict__ logA3,
                         const float* __restrict__ logpi1,
                         const float* __restrict__ logpi2,
                         const float* __restrict__ logpi3,
                         float* __restrict__ out)
{
    __shared__ __align__(16) float alpha[2048];      // [p1*128 + p2*8 + p3]
    __shared__ __align__(16) float c1buf[16 * 164];  // [d1*164 + p3*20 + p2]
    __shared__ __align__(16) float c2buf[16 * 168];  // [d1*168 + d2*10 + p3]
    __shared__ float wmEm[8];
    __shared__ float wmA[8];
    __shared__ float sD[1];
    __shared__ float lgtbl[32];
    __shared__ double lgpart[8];
    __shared__ float sredf[8];

    const int tid  = threadIdx.x;
    const int lane = tid & 63;
    const int wv   = tid >> 6;
    const int s0   = tid * 4;
    const int d1   = s0 >> 7;
    const int d2   = (s0 >> 3) & 15;
    const int d3b  = s0 & 7;              // 0 or 4; owns d3b..d3b+3

    // Stage-1: output rows r0..r0+3 (wave-uniform), column cS1 = p2*8+p3
    const int cS1 = tid & 127;
    const int r0  = (tid >> 7) << 2;                 // {0,4,8,12}
    const int c1w = (cS1 & 7) * 20 + (cS1 >> 3);     // p3*20 + p2, + (r0+k)*164
    // Stage-2: output rows r2..r2+3 (wave-uniform), column (d1u, p3u)
    const int u    = tid & 127;
    const int d1u  = u >> 3;
    const int p3u  = u & 7;
    const int r2   = (tid >> 7) << 2;
    const int c1r  = d1u * 164 + p3u * 20;           // + p2 (contig -> b128)
    const int c2w  = d1u * 168 + p3u;                // + (r2+k)*10
    // Stage-3: c2 column (d1,d2) owned by this thread
    const int c2r  = d1 * 168 + d2 * 10;             // + p3 (contig -> b64 pairs)

    if (tid < 32) lgtbl[tid] = lgammaf((float)tid + 1.0f);

    // ---- A rows: A1 rows r0..r0+3 in VGPRs, A2 rows r2..r2+3 in SGPRs, A3 in VGPRs ----
    float sa1[4][16];
    #pragma unroll
    for (int k = 0; k < 4; ++k)
        #pragma unroll
        for (int p = 0; p < 16; ++p)
            sa1[k][p] = __expf(logA1[(r0 + k) * 16 + p]);
    float sa2[4][16];
    #pragma unroll
    for (int k = 0; k < 4; ++k)
        #pragma unroll
        for (int p = 0; p < 16; ++p)
            sa2[k][p] = rfl(__expf(logA2[(r2 + k) * 16 + p]));
    float a3c[4][8];
    #pragma unroll
    for (int k = 0; k < 4; ++k)
        #pragma unroll
        for (int p = 0; p < 8; ++p)
            a3c[k][p] = __expf(logA3[(d3b + k) * 8 + p]);

    // ---- emission params: rl[k][m] = log(lamc), lamsum[k] ----
    float rl[4][16];
    float lamsum[4];
    #pragma unroll
    for (int k = 0; k < 4; ++k) {
        float ls = 0.f;
        #pragma unroll
        for (int m = 0; m < MDIM; ++m) {
            float la = lam1[d1 * MDIM + m] + lam2[d2 * MDIM + m]
                     + lam3[(d3b + k) * MDIM + m];
            ls += la;
            rl[k][m] = __logf(la);
        }
        lamsum[k] = ls;
    }
    __syncthreads();

    // ---- sum_t sum_m lgamma(x+1): state-uniform, subtract at end ----
    {
        double lg = 0.0;
        const int4* x4 = (const int4*)x;
        for (int i = tid; i < TMAX * MDIM / 4; i += NTHR) {
            int4 v = x4[i];
            lg += (double)(lgtbl[v.x & 31] + lgtbl[v.y & 31] +
                           lgtbl[v.z & 31] + lgtbl[v.w & 31]);
        }
        lg = waveSumD(lg);
        if (lane == 0) lgpart[wv] = lg;
    }

    // ---- t = 0 ----
    double OFF = 0.0;
    {
        float va[4];
        float lp12 = logpi1[d1] + logpi2[d2];
        #pragma unroll
        for (int k = 0; k < 4; ++k) {
            float dot = 0.f;
            #pragma unroll
            for (int m = 0; m < MDIM; ++m)
                dot = fmaf((float)x[m], rl[k][m], dot);
            va[k] = dot - lamsum[k] + lp12 + logpi3[d3b + k];
        }
        float wm = waveMax64(fmaxf(fmaxf(va[0], va[1]), fmaxf(va[2], va[3])));
        if (lane == 0) wmEm[wv] = wm;
        __syncthreads();
        float M0 = waveMax64(wmEm[lane & 7]);
        float4 av;
        av.x = __expf(va[0] - M0); av.y = __expf(va[1] - M0);
        av.z = __expf(va[2] - M0); av.w = __expf(va[3] - M0);
        *(float4*)(alpha + s0) = av;
        float wA = waveMax64(fmaxf(fmaxf(av.x, av.y), fmaxf(av.z, av.w)));
        if (lane == 0) wmA[wv] = wA;
        if (tid == 0) OFF = (double)M0;
        __syncthreads();
    }

    float mpLog = 0.f, Dv = 0.f;

    // ---- main sequential recurrence ----
    for (int t = 1; t < TMAX; ++t) {
        // x row via uniform pointer -> scalar loads
        const int* __restrict__ xr = x + (t << 4);
        float xf[16];
        #pragma unroll
        for (int m = 0; m < MDIM; ++m) xf[m] = (float)xr[m];

        // wave 0: combine previous-step alpha maxes (overlaps S1 window)
        if (wv == 0) {
            float mp = waveMax64(wmA[lane & 7]);
            mpLog = __logf(fmaxf(mp, 1e-30f));
        }

        // Stage 1: c1[r0+k][cS1] = sum_p1 A1[r0+k,p1] * alpha[p1*128 + cS1]
        {
            float a0 = 0.f, a1 = 0.f, a2 = 0.f, a3 = 0.f;
            #pragma unroll
            for (int p1 = 0; p1 < 16; ++p1) {
                float av = alpha[p1 * 128 + cS1];
                a0 = fmaf(sa1[0][p1], av, a0);
                a1 = fmaf(sa1[1][p1], av, a1);
                a2 = fmaf(sa1[2][p1], av, a2);
                a3 = fmaf(sa1[3][p1], av, a3);
            }
            c1buf[(r0 + 0) * 164 + c1w] = a0;
            c1buf[(r0 + 1) * 164 + c1w] = a1;
            c1buf[(r0 + 2) * 164 + c1w] = a2;
            c1buf[(r0 + 3) * 164 + c1w] = a3;
        }

        // emission for this thread's 4 states
        float em[4];
        #pragma unroll
        for (int k = 0; k < 4; ++k) {
            float dd = 0.f;
            #pragma unroll
            for (int m = 0; m < MDIM; ++m)
                dd = fmaf(xf[m], rl[k][m], dd);
            em[k] = dd - lamsum[k];
        }
        float wmE = waveMax64(fmaxf(fmaxf(em[0], em[1]), fmaxf(em[2], em[3])));
        if (lane == 0) wmEm[wv] = wmE;
        __syncthreads();   // B1: c1, wmEm ready

        // wave 0: publish D = Mt + log(mp) (overlaps S2 window)
        if (wv == 0) {
            float Mt = waveMax64(wmEm[lane & 7]);
            Dv = Mt + mpLog;
            if (lane == 0) sD[0] = Dv;
        }

        // Stage 2: c2[d1u][r2+k][p3u] = sum_p2 A2[r2+k,p2] * c1[d1u][p3u*20+p2]
        {
            float b0 = 0.f, b1 = 0.f, b2 = 0.f, b3 = 0.f;
            const float4* c1v = (const float4*)(c1buf + c1r);
            #pragma unroll
            for (int p = 0; p < 4; ++p) {
                float4 q = c1v[p];
                b0 = fmaf(sa2[0][4*p+0], q.x, b0); b1 = fmaf(sa2[1][4*p+0], q.x, b1);
                b2 = fmaf(sa2[2][4*p+0], q.x, b2); b3 = fmaf(sa2[3][4*p+0], q.x, b3);
                b0 = fmaf(sa2[0][4*p+1], q.y, b0); b1 = fmaf(sa2[1][4*p+1], q.y, b1);
                b2 = fmaf(sa2[2][4*p+1], q.y, b2); b3 = fmaf(sa2[3][4*p+1], q.y, b3);
                b0 = fmaf(sa2[0][4*p+2], q.z, b0); b1 = fmaf(sa2[1][4*p+2], q.z, b1);
                b2 = fmaf(sa2[2][4*p+2], q.z, b2); b3 = fmaf(sa2[3][4*p+2], q.z, b3);
                b0 = fmaf(sa2[0][4*p+3], q.w, b0); b1 = fmaf(sa2[1][4*p+3], q.w, b1);
                b2 = fmaf(sa2[2][4*p+3], q.w, b2); b3 = fmaf(sa2[3][4*p+3], q.w, b3);
            }
            c2buf[c2w + (r2 + 0) * 10] = b0;
            c2buf[c2w + (r2 + 1) * 10] = b1;
            c2buf[c2w + (r2 + 2) * 10] = b2;
            c2buf[c2w + (r2 + 3) * 10] = b3;
        }
        __syncthreads();   // B2: c2, sD ready

        // Stage 3 + pointwise
        {
            float D = (wv == 0) ? Dv : sD[0];
            float cv[8];
            const float2* c2v = (const float2*)(c2buf + c2r);
            #pragma unroll
            for (int j = 0; j < 4; ++j) {
                float2 q = c2v[j];
                cv[2*j] = q.x; cv[2*j+1] = q.y;
            }
            float4 nu;
            float g0 = 0.f, g1 = 0.f, g2 = 0.f, g3 = 0.f;
            #pragma unroll
            for (int p = 0; p < 8; ++p) {
                g0 = fmaf(a3c[0][p], cv[p], g0);
                g1 = fmaf(a3c[1][p], cv[p], g1);
                g2 = fmaf(a3c[2][p], cv[p], g2);
                g3 = fmaf(a3c[3][p], cv[p], g3);
            }
            nu.x = __expf(em[0] - D) * g0;
            nu.y = __expf(em[1] - D) * g1;
            nu.z = __expf(em[2] - D) * g2;
            nu.w = __expf(em[3] - D) * g3;
            *(float4*)(alpha + s0) = nu;
            float wA = waveMax64(fmaxf(fmaxf(nu.x, nu.y), fmaxf(nu.z, nu.w)));
            if (lane == 0) wmA[wv] = wA;
            if (tid == 0) OFF += (double)D;
        }
        __syncthreads();   // B3: alpha, wmA ready
    }

    // ---- final: logp = OFF + log(sum_s alpha) - lgam_total ----
    {
        float su = alpha[s0] + alpha[s0 + 1] + alpha[s0 + 2] + alpha[s0 + 3];
        su = waveSumF(su);
        if (lane == 0) sredf[wv] = su;
        __syncthreads();
        if (tid == 0) {
            float tot = 0.f;
            #pragma unroll
            for (int i = 0; i < 8; ++i) tot += sredf[i];
            double lgt = 0.0;
            #pragma unroll
            for (int i = 0; i < 8; ++i) lgt += lgpart[i];
            double res = OFF + (double)__logf(tot) - lgt;
            out[0] = (float)res;
        }
    }
}

extern "C" void kernel_launch(void* const* d_in, const int* in_sizes, int n_in,
                              void* d_out, int out_size, void* d_ws, size_t ws_size,
                              hipStream_t stream) {
    const int*   x      = (const int*)  d_in[0];
    const float* lam1   = (const float*)d_in[1];
    const float* lam2   = (const float*)d_in[2];
    const float* lam3   = (const float*)d_in[3];
    const float* logA1  = (const float*)d_in[4];
    const float* logA2  = (const float*)d_in[5];
    const float* logA3  = (const float*)d_in[6];
    const float* logpi1 = (const float*)d_in[7];
    const float* logpi2 = (const float*)d_in[8];
    const float* logpi3 = (const float*)d_in[9];
    float* out = (float*)d_out;

    fhmm_forward_kernel<<<dim3(1), dim3(NTHR), 0, stream>>>(
        x, lam1, lam2, lam3, logA1, logA2, logA3, logpi1, logpi2, logpi3, out);
}